// Round 1
// baseline (1372.644 us; speedup 1.0000x reference)
//
#include <hip/hip_runtime.h>
#include <math.h>

#define LSEQ 512
#define BATCH 64
#define EDIM 256
#define HD 128            // H2
#define G4 512            // 4*H2
#define NTAG 9
#define MTOT (LSEQ*BATCH) // 32768

__device__ __forceinline__ float sigf(float x){ return 1.0f/(1.0f+expf(-x)); }

// ---------------- GEMM: gx[dir][l*64+b][j] = emb[sent[b][l]] . w_ih[j] + bias ----------------
#define BM 64
#define BN 64
#define BKK 32
__global__ __launch_bounds__(256) void gx_gemm(
    const int* __restrict__ sent, const float* __restrict__ emb,
    const float* __restrict__ wf, const float* __restrict__ wb,
    const float* __restrict__ bf, const float* __restrict__ bb,
    float* __restrict__ gx)
{
    __shared__ float As[BKK][BM];
    __shared__ float Bs[BKK][BN];
    __shared__ int   sidx[BM];
    const int bm0 = blockIdx.x * BM;
    const int bn0 = blockIdx.y * BN;
    const int tid = threadIdx.x;
    if (tid < BM) {
        int m = bm0 + tid;
        int l = m >> 6, b = m & 63;
        sidx[tid] = sent[b * LSEQ + l];
    }
    __syncthreads();
    const int lm = tid & 63;
    const int lw = tid >> 6;        // 0..3 (wave id)
    const int tm = tid >> 4;        // 0..15
    const int tn = tid & 15;        // 0..15

    const int nrow = bn0 + lm;
    const float* bp = (nrow < G4) ? (wf + (size_t)nrow * EDIM)
                                  : (wb + (size_t)(nrow - G4) * EDIM);
    const int arow = sidx[lm];
    const float* ap = emb + (size_t)arow * EDIM;

    float acc[4][4];
    #pragma unroll
    for (int i=0;i<4;i++)
        #pragma unroll
        for (int j=0;j<4;j++) acc[i][j]=0.f;

    for (int k0 = 0; k0 < EDIM; k0 += BKK) {
        __syncthreads();
        #pragma unroll
        for (int q=0;q<2;q++){
            int kk = lw*8 + q*4;
            float4 av = *(const float4*)(ap + k0 + kk);
            As[kk+0][lm]=av.x; As[kk+1][lm]=av.y; As[kk+2][lm]=av.z; As[kk+3][lm]=av.w;
            float4 bv = *(const float4*)(bp + k0 + kk);
            Bs[kk+0][lm]=bv.x; Bs[kk+1][lm]=bv.y; Bs[kk+2][lm]=bv.z; Bs[kk+3][lm]=bv.w;
        }
        __syncthreads();
        #pragma unroll
        for (int k=0;k<BKK;k++){
            float4 a = *(const float4*)&As[k][tm*4];
            float4 b = *(const float4*)&Bs[k][tn*4];
            acc[0][0]+=a.x*b.x; acc[0][1]+=a.x*b.y; acc[0][2]+=a.x*b.z; acc[0][3]+=a.x*b.w;
            acc[1][0]+=a.y*b.x; acc[1][1]+=a.y*b.y; acc[1][2]+=a.y*b.z; acc[1][3]+=a.y*b.w;
            acc[2][0]+=a.z*b.x; acc[2][1]+=a.z*b.y; acc[2][2]+=a.z*b.z; acc[2][3]+=a.z*b.w;
            acc[3][0]+=a.w*b.x; acc[3][1]+=a.w*b.y; acc[3][2]+=a.w*b.z; acc[3][3]+=a.w*b.w;
        }
    }
    const int n0  = bn0 + tn*4;
    const int dir = n0 >> 9;
    const int jj0 = n0 & 511;
    float4 bias;
    {
        const float* bbase = (n0 < G4) ? bf : bb;
        int nb = (n0 < G4) ? n0 : (n0 - G4);
        bias.x = bbase[nb+0]; bias.y = bbase[nb+1]; bias.z = bbase[nb+2]; bias.w = bbase[nb+3];
    }
    #pragma unroll
    for (int i=0;i<4;i++){
        int m = bm0 + tm*4 + i;
        float4 v;
        v.x=acc[i][0]+bias.x; v.y=acc[i][1]+bias.y; v.z=acc[i][2]+bias.z; v.w=acc[i][3]+bias.w;
        *(float4*)(gx + (size_t)dir*MTOT*G4 + (size_t)m*G4 + jj0) = v;
    }
}

// ---------------- LSTM recurrence: 128 WGs = (dir, b); w_hh row per thread in VGPRs ----------------
__global__ __launch_bounds__(512) void lstm_rec(
    const float* __restrict__ gx,
    const float* __restrict__ whf, const float* __restrict__ whb,
    const int* __restrict__ pm,
    float* __restrict__ lout)
{
    const int wg  = blockIdx.x;      // 0..127
    const int dir = wg >> 6;
    const int b   = wg & 63;
    const int j   = threadIdx.x;     // 0..511

    const float* wr = (dir ? whb : whf) + (size_t)j * HD;
    float w[HD];
    #pragma unroll
    for (int k=0;k<HD;k+=4){
        float4 v = *(const float4*)(wr + k);
        w[k]=v.x; w[k+1]=v.y; w[k+2]=v.z; w[k+3]=v.w;
    }
    __shared__ float hsh[HD];
    __shared__ float act[G4];
    if (j < HD) hsh[j] = 0.f;
    float c = 0.f, h = 0.f;
    const float* gxp = gx + (size_t)dir*MTOT*G4 + (size_t)b*G4 + j;
    const int*  pmb  = pm + b*LSEQ;
    float* op = lout + (size_t)b*256 + dir*HD + j;   // used only when j<HD
    const int gate = j >> 7;
    __syncthreads();

    for (int s=0; s<LSEQ; s++){
        const int l = dir ? (LSEQ-1-s) : s;
        float g = gxp[(size_t)l * (BATCH*G4)];
        float g0=0.f,g1=0.f,g2=0.f,g3=0.f;
        #pragma unroll
        for (int k=0;k<HD;k+=16){
            float4 h0 = *(const float4*)&hsh[k];
            float4 h1 = *(const float4*)&hsh[k+4];
            float4 h2 = *(const float4*)&hsh[k+8];
            float4 h3 = *(const float4*)&hsh[k+12];
            g0 += h0.x*w[k+0]  + h0.y*w[k+1]  + h0.z*w[k+2]  + h0.w*w[k+3];
            g1 += h1.x*w[k+4]  + h1.y*w[k+5]  + h1.z*w[k+6]  + h1.w*w[k+7];
            g2 += h2.x*w[k+8]  + h2.y*w[k+9]  + h2.z*w[k+10] + h2.w*w[k+11];
            g3 += h3.x*w[k+12] + h3.y*w[k+13] + h3.z*w[k+14] + h3.w*w[k+15];
        }
        g += (g0+g1)+(g2+g3);
        float a = (gate==2) ? tanhf(g) : sigf(g);
        act[j] = a;
        __syncthreads();
        if (j < HD) {
            float i_ = act[j], f_ = act[HD+j], gg = act[2*HD+j], o_ = act[3*HD+j];
            float cn = f_*c + i_*gg;
            float hn = o_*tanhf(cn);
            float y;
            if (pmb[l]) { c = cn; h = hn; y = hn; } else { y = 0.f; }
            hsh[j] = h;
            op[(size_t)l * (BATCH*256)] = y;
        }
        __syncthreads();
    }
}

// ---------------- Emissions: e[m][t] = lout[m] . W_out[t] + b_out[t] ----------------
__global__ __launch_bounds__(256) void emis_kernel(
    const float* __restrict__ xin, const float* __restrict__ Wo,
    const float* __restrict__ bo, float* __restrict__ e)
{
    __shared__ float Wl[NTAG*260];   // padded rows (260) to break LDS bank aliasing
    const int tid = threadIdx.x;
    for (int i=tid; i<NTAG*256; i+=256) Wl[(i>>8)*260 + (i&255)] = Wo[i];
    __syncthreads();
    const int m0 = blockIdx.x * 32;
    const int tg = tid & 7;          // tag 0..7 (tg==0 also does tag 8)
    const int r  = tid >> 3;         // row 0..31
    const float* xr = xin + (size_t)(m0 + r) * 256;
    float a0=0.f, a1=0.f;
    #pragma unroll 8
    for (int k=0;k<256;k+=4){
        float4 xv = *(const float4*)(xr + k);
        float4 w0 = *(const float4*)&Wl[tg*260 + k];
        a0 += xv.x*w0.x + xv.y*w0.y + xv.z*w0.z + xv.w*w0.w;
        if (tg == 0) {
            float4 w8 = *(const float4*)&Wl[8*260 + k];
            a1 += xv.x*w8.x + xv.y*w8.y + xv.z*w8.z + xv.w*w8.w;
        }
    }
    e[(size_t)(m0+r)*NTAG + tg] = a0 + bo[tg];
    if (tg == 0) e[(size_t)(m0+r)*NTAG + 8] = a1 + bo[8];
}

// ---------------- CRF: role 0 = logZ scan, role 1 = Viterbi scan, role 2 = gold score ----------------
__global__ __launch_bounds__(576) void crf_kernel(
    const float* __restrict__ e, const int* __restrict__ pm,
    const int* __restrict__ tags,
    const float* __restrict__ stt, const float* __restrict__ ent,
    const float* __restrict__ trans,
    float* __restrict__ logZ, float* __restrict__ num,
    unsigned char* __restrict__ hist, int* __restrict__ bestl)
{
    __shared__ float sc[2][BATCH][NTAG];
    __shared__ float trl[NTAG*NTAG];
    __shared__ float stl[NTAG], enl[NTAG];
    const int tid = threadIdx.x;     // 0..575
    const int role = blockIdx.x;
    if (tid < 81) trl[tid] = trans[tid];
    if (tid < 9) { stl[tid] = stt[tid]; enl[tid] = ent[tid]; }
    __syncthreads();
    const int b = tid / 9, tp = tid % 9;

    if (role == 0) {
        sc[0][b][tp] = stl[tp] + e[(size_t)b*NTAG + tp];
        __syncthreads();
        int cur = 0;
        float ev = e[(size_t)(1*BATCH + b)*NTAG + tp];
        for (int l=1; l<LSEQ; l++){
            float evn = (l+1<LSEQ) ? e[(size_t)((l+1)*BATCH + b)*NTAG + tp] : 0.f;
            float mx = -INFINITY;
            #pragma unroll
            for (int t=0;t<NTAG;t++) mx = fmaxf(mx, sc[cur][b][t] + trl[t*NTAG+tp]);
            float ssum = 0.f;
            #pragma unroll
            for (int t=0;t<NTAG;t++) ssum += expf(sc[cur][b][t] + trl[t*NTAG+tp] - mx);
            float nxt = mx + logf(ssum) + ev;
            sc[cur^1][b][tp] = pm[b*LSEQ + l] ? nxt : sc[cur][b][tp];
            __syncthreads();
            cur ^= 1;
            ev = evn;
        }
        if (tp == 0) {
            float mx = -INFINITY;
            for (int t=0;t<NTAG;t++) mx = fmaxf(mx, sc[cur][b][t] + enl[t]);
            float ssum = 0.f;
            for (int t=0;t<NTAG;t++) ssum += expf(sc[cur][b][t] + enl[t] - mx);
            logZ[b] = mx + logf(ssum);
        }
    } else if (role == 1) {
        sc[0][b][tp] = stl[tp] + e[(size_t)b*NTAG + tp];
        __syncthreads();
        int cur = 0;
        float ev = e[(size_t)(1*BATCH + b)*NTAG + tp];
        for (int l=1; l<LSEQ; l++){
            float evn = (l+1<LSEQ) ? e[(size_t)((l+1)*BATCH + b)*NTAG + tp] : 0.f;
            float bv = -INFINITY; int bi = 0;
            #pragma unroll
            for (int t=0;t<NTAG;t++){
                float v = sc[cur][b][t] + trl[t*NTAG+tp];
                if (v > bv) { bv = v; bi = t; }   // strict > : first max (matches jnp.argmax)
            }
            hist[(size_t)(l-1)*1024 + b*16 + tp] = (unsigned char)bi;
            sc[cur^1][b][tp] = bv + ev;
            __syncthreads();
            cur ^= 1;
            ev = evn;
        }
        if (tp == 0) {
            float bv = -INFINITY; int bi = 0;
            for (int t=0;t<NTAG;t++){
                float v = sc[cur][b][t] + enl[t];
                if (v > bv) { bv = v; bi = t; }
            }
            bestl[b] = bi;
        }
    } else {
        __shared__ float ps[BATCH][NTAG];
        __shared__ int   cs[BATCH][NTAG];
        float part = 0.f; int cnt = 0;
        for (int l = tp; l < LSEQ; l += 9) {
            int mt = pm[b*LSEQ + l];
            cnt += (mt != 0);
            if (l >= 1 && mt) {
                int tl = tags[b*LSEQ + l];
                int tq = tags[b*LSEQ + l - 1];
                part += trl[tq*NTAG + tl] + e[(size_t)(l*BATCH + b)*NTAG + tl];
            }
        }
        ps[b][tp] = part; cs[b][tp] = cnt;
        __syncthreads();
        if (tp == 0) {
            float s = 0.f; int cc = 0;
            for (int q=0;q<9;q++){ s += ps[b][q]; cc += cs[b][q]; }
            int t0 = tags[b*LSEQ];
            float nb = stl[t0] + e[(size_t)b*NTAG + t0] + s;
            nb += enl[tags[b*LSEQ + (cc-1)]];
            num[b] = nb;
        }
    }
}

// ---------------- Backtrace + loss ----------------
__global__ __launch_bounds__(64) void backtrace_kernel(
    const unsigned char* __restrict__ hist, const int* __restrict__ bestl,
    const int* __restrict__ pm, const float* __restrict__ num,
    const float* __restrict__ logZ, float* __restrict__ out)
{
    const int b = threadIdx.x;       // 0..63, one wave
    float d = num[b] - logZ[b];
    #pragma unroll
    for (int off=32; off; off>>=1) d += __shfl_down(d, off);
    if (b == 0) out[0] = -d * (1.0f/64.0f);
    int tag = bestl[b];
    out[1 + b*LSEQ + (LSEQ-1)] = (float)(tag * pm[b*LSEQ + (LSEQ-1)]);
    #pragma unroll 8
    for (int l = LSEQ-2; l >= 0; l--) {
        uint4 row = *(const uint4*)(hist + (size_t)l*1024 + b*16);  // addr independent of tag -> pipelined
        unsigned int wlo  = (tag & 4) ? row.y : row.x;
        unsigned int wsel = (tag & 8) ? row.z : wlo;
        tag = (int)((wsel >> ((tag & 3) * 8)) & 255u);
        out[1 + b*LSEQ + l] = (float)(tag * pm[b*LSEQ + l]);
    }
}

extern "C" void kernel_launch(void* const* d_in, const int* in_sizes, int n_in,
                              void* d_out, int out_size, void* d_ws, size_t ws_size,
                              hipStream_t stream)
{
    (void)in_sizes; (void)n_in; (void)out_size; (void)ws_size;
    const int*   sent  = (const int*)  d_in[0];
    const int*   tags  = (const int*)  d_in[1];
    const int*   pm    = (const int*)  d_in[2];
    // d_in[3] = batch_sequence_max_len (== 512)
    const float* emb   = (const float*)d_in[4];
    const float* wihf  = (const float*)d_in[5];
    const float* whhf  = (const float*)d_in[6];
    const float* bf    = (const float*)d_in[7];
    const float* wihb  = (const float*)d_in[8];
    const float* whhb  = (const float*)d_in[9];
    const float* bb    = (const float*)d_in[10];
    const float* Wo    = (const float*)d_in[11];
    const float* bo    = (const float*)d_in[12];
    const float* stt   = (const float*)d_in[13];
    const float* ent   = (const float*)d_in[14];
    const float* trans = (const float*)d_in[15];

    char* ws = (char*)d_ws;
    float* gx            = (float*)(ws);                       // 2*32768*512*4   = 134217728 B
    float* lout          = (float*)(ws + 134217728);           // 32768*256*4     =  33554432 B
    float* emis          = (float*)(ws + 167772160);           // 32768*9*4       =   1179648 B
    unsigned char* hist  = (unsigned char*)(ws + 168951808);   // 511*64*16       =    523264 B
    float* numb          = (float*)(ws + 169475072);           // 64*4
    float* logZ          = (float*)(ws + 169475328);           // 64*4
    int*   bestl         = (int*)  (ws + 169475584);           // 64*4

    dim3 g1(MTOT/BM, (2*G4)/BN);   // 512 x 16
    gx_gemm<<<g1, 256, 0, stream>>>(sent, emb, wihf, wihb, bf, bb, gx);
    lstm_rec<<<128, 512, 0, stream>>>(gx, whhf, whhb, pm, lout);
    emis_kernel<<<MTOT/32, 256, 0, stream>>>(lout, Wo, bo, emis);
    crf_kernel<<<3, 576, 0, stream>>>(emis, pm, tags, stt, ent, trans, logZ, numb, hist, bestl);
    backtrace_kernel<<<1, 64, 0, stream>>>(hist, bestl, pm, numb, logZ, (float*)d_out);
}

// Round 2
// 997.872 us; speedup vs baseline: 1.3756x; 1.3756x over previous
//
#include <hip/hip_runtime.h>
#include <math.h>

#define LSEQ 512
#define BATCH 64
#define EDIM 256
#define HD 128            // H2
#define G4 512            // 4*H2
#define NTAG 9
#define MTOT (LSEQ*BATCH) // 32768

__device__ __forceinline__ float sigf(float x){ return 1.0f/(1.0f+expf(-x)); }

// ---------------- GEMM: gx[dir][l*64+b][j] = emb[sent[b][l]] . w_ih[j] + bias ----------------
#define BM 64
#define BN 64
#define BKK 32
__global__ __launch_bounds__(256) void gx_gemm(
    const int* __restrict__ sent, const float* __restrict__ emb,
    const float* __restrict__ wf, const float* __restrict__ wb,
    const float* __restrict__ bf, const float* __restrict__ bb,
    float* __restrict__ gx)
{
    __shared__ float As[BKK][BM];
    __shared__ float Bs[BKK][BN];
    __shared__ int   sidx[BM];
    const int bm0 = blockIdx.x * BM;
    const int bn0 = blockIdx.y * BN;
    const int tid = threadIdx.x;
    if (tid < BM) {
        int m = bm0 + tid;
        int l = m >> 6, b = m & 63;
        sidx[tid] = sent[b * LSEQ + l];
    }
    __syncthreads();
    const int lm = tid & 63;
    const int lw = tid >> 6;        // 0..3 (wave id)
    const int tm = tid >> 4;        // 0..15
    const int tn = tid & 15;        // 0..15

    const int nrow = bn0 + lm;
    const float* bp = (nrow < G4) ? (wf + (size_t)nrow * EDIM)
                                  : (wb + (size_t)(nrow - G4) * EDIM);
    const int arow = sidx[lm];
    const float* ap = emb + (size_t)arow * EDIM;

    float acc[4][4];
    #pragma unroll
    for (int i=0;i<4;i++)
        #pragma unroll
        for (int j=0;j<4;j++) acc[i][j]=0.f;

    for (int k0 = 0; k0 < EDIM; k0 += BKK) {
        __syncthreads();
        #pragma unroll
        for (int q=0;q<2;q++){
            int kk = lw*8 + q*4;
            float4 av = *(const float4*)(ap + k0 + kk);
            As[kk+0][lm]=av.x; As[kk+1][lm]=av.y; As[kk+2][lm]=av.z; As[kk+3][lm]=av.w;
            float4 bv = *(const float4*)(bp + k0 + kk);
            Bs[kk+0][lm]=bv.x; Bs[kk+1][lm]=bv.y; Bs[kk+2][lm]=bv.z; Bs[kk+3][lm]=bv.w;
        }
        __syncthreads();
        #pragma unroll
        for (int k=0;k<BKK;k++){
            float4 a = *(const float4*)&As[k][tm*4];
            float4 b = *(const float4*)&Bs[k][tn*4];
            acc[0][0]+=a.x*b.x; acc[0][1]+=a.x*b.y; acc[0][2]+=a.x*b.z; acc[0][3]+=a.x*b.w;
            acc[1][0]+=a.y*b.x; acc[1][1]+=a.y*b.y; acc[1][2]+=a.y*b.z; acc[1][3]+=a.y*b.w;
            acc[2][0]+=a.z*b.x; acc[2][1]+=a.z*b.y; acc[2][2]+=a.z*b.z; acc[2][3]+=a.z*b.w;
            acc[3][0]+=a.w*b.x; acc[3][1]+=a.w*b.y; acc[3][2]+=a.w*b.z; acc[3][3]+=a.w*b.w;
        }
    }
    const int n0  = bn0 + tn*4;
    const int dir = n0 >> 9;
    const int jj0 = n0 & 511;
    float4 bias;
    {
        const float* bbase = (n0 < G4) ? bf : bb;
        int nb = (n0 < G4) ? n0 : (n0 - G4);
        bias.x = bbase[nb+0]; bias.y = bbase[nb+1]; bias.z = bbase[nb+2]; bias.w = bbase[nb+3];
    }
    #pragma unroll
    for (int i=0;i<4;i++){
        int m = bm0 + tm*4 + i;
        float4 v;
        v.x=acc[i][0]+bias.x; v.y=acc[i][1]+bias.y; v.z=acc[i][2]+bias.z; v.w=acc[i][3]+bias.w;
        *(float4*)(gx + (size_t)dir*MTOT*G4 + (size_t)m*G4 + jj0) = v;
    }
}

// ---------------- LSTM recurrence: 128 WGs = (dir, b); w_hh row per thread in VGPRs ----------------
__global__ __launch_bounds__(512) void lstm_rec(
    const float* __restrict__ gx,
    const float* __restrict__ whf, const float* __restrict__ whb,
    const int* __restrict__ pm,
    float* __restrict__ lout)
{
    const int wg  = blockIdx.x;      // 0..127
    const int dir = wg >> 6;
    const int b   = wg & 63;
    const int j   = threadIdx.x;     // 0..511

    const float* wr = (dir ? whb : whf) + (size_t)j * HD;
    float w[HD];
    #pragma unroll
    for (int k=0;k<HD;k+=4){
        float4 v = *(const float4*)(wr + k);
        w[k]=v.x; w[k+1]=v.y; w[k+2]=v.z; w[k+3]=v.w;
    }
    __shared__ float hsh[HD];
    __shared__ float act[G4];
    if (j < HD) hsh[j] = 0.f;
    float c = 0.f, h = 0.f;
    const float* gxp = gx + (size_t)dir*MTOT*G4 + (size_t)b*G4 + j;
    const int*  pmb  = pm + b*LSEQ;
    float* op = lout + (size_t)b*256 + dir*HD + j;   // used only when j<HD
    const int gate = j >> 7;
    __syncthreads();

    for (int s=0; s<LSEQ; s++){
        const int l = dir ? (LSEQ-1-s) : s;
        float g = gxp[(size_t)l * (BATCH*G4)];
        float g0=0.f,g1=0.f,g2=0.f,g3=0.f;
        #pragma unroll
        for (int k=0;k<HD;k+=16){
            float4 h0 = *(const float4*)&hsh[k];
            float4 h1 = *(const float4*)&hsh[k+4];
            float4 h2 = *(const float4*)&hsh[k+8];
            float4 h3 = *(const float4*)&hsh[k+12];
            g0 += h0.x*w[k+0]  + h0.y*w[k+1]  + h0.z*w[k+2]  + h0.w*w[k+3];
            g1 += h1.x*w[k+4]  + h1.y*w[k+5]  + h1.z*w[k+6]  + h1.w*w[k+7];
            g2 += h2.x*w[k+8]  + h2.y*w[k+9]  + h2.z*w[k+10] + h2.w*w[k+11];
            g3 += h3.x*w[k+12] + h3.y*w[k+13] + h3.z*w[k+14] + h3.w*w[k+15];
        }
        g += (g0+g1)+(g2+g3);
        float a = (gate==2) ? tanhf(g) : sigf(g);
        act[j] = a;
        __syncthreads();
        if (j < HD) {
            float i_ = act[j], f_ = act[HD+j], gg = act[2*HD+j], o_ = act[3*HD+j];
            float cn = f_*c + i_*gg;
            float hn = o_*tanhf(cn);
            float y;
            if (pmb[l]) { c = cn; h = hn; y = hn; } else { y = 0.f; }
            hsh[j] = h;
            op[(size_t)l * (BATCH*256)] = y;
        }
        __syncthreads();
    }
}

// ---------------- Emissions: e[m][t] = lout[m] . W_out[t] + b_out[t] ----------------
__global__ __launch_bounds__(256) void emis_kernel(
    const float* __restrict__ xin, const float* __restrict__ Wo,
    const float* __restrict__ bo, float* __restrict__ e)
{
    __shared__ float Wl[NTAG*260];   // padded rows (260) to break LDS bank aliasing
    const int tid = threadIdx.x;
    for (int i=tid; i<NTAG*256; i+=256) Wl[(i>>8)*260 + (i&255)] = Wo[i];
    __syncthreads();
    const int m0 = blockIdx.x * 32;
    const int tg = tid & 7;          // tag 0..7 (tg==0 also does tag 8)
    const int r  = tid >> 3;         // row 0..31
    const float* xr = xin + (size_t)(m0 + r) * 256;
    float a0=0.f, a1=0.f;
    #pragma unroll 8
    for (int k=0;k<256;k+=4){
        float4 xv = *(const float4*)(xr + k);
        float4 w0 = *(const float4*)&Wl[tg*260 + k];
        a0 += xv.x*w0.x + xv.y*w0.y + xv.z*w0.z + xv.w*w0.w;
        if (tg == 0) {
            float4 w8 = *(const float4*)&Wl[8*260 + k];
            a1 += xv.x*w8.x + xv.y*w8.y + xv.z*w8.z + xv.w*w8.w;
        }
    }
    e[(size_t)(m0+r)*NTAG + tg] = a0 + bo[tg];
    if (tg == 0) e[(size_t)(m0+r)*NTAG + 8] = a1 + bo[8];
}

// ---------------- CRF scan: barrier-free. Blocks 0..9: 7 batches/wave (9 lanes each),
// fused logZ (logsumexp) + Viterbi (argmax) recursions via __shfl broadcast.
// Block 10: gold-path score (1 lane per batch). ----------------
__global__ __launch_bounds__(64) void crf_scan(
    const float* __restrict__ e, const int* __restrict__ pm,
    const int* __restrict__ tags,
    const float* __restrict__ stt, const float* __restrict__ ent,
    const float* __restrict__ trans,
    float* __restrict__ logZ, float* __restrict__ num,
    unsigned char* __restrict__ hist, int* __restrict__ bestl)
{
    const int blk  = blockIdx.x;
    const int lane = threadIdx.x;

    if (blk < 10) {
        const int bw = lane / 9;          // sub-batch within wave, 0..6 (lane 63 idle)
        const int tp = lane % 9;
        const int b  = blk * 7 + bw;
        const bool act = (bw < 7) && (b < BATCH);
        const int gbase = bw * 9;         // first lane of my 9-lane group

        float trc[NTAG];                  // trans column: trc[t] = trans[t][tp]
        #pragma unroll
        for (int t=0;t<NTAG;t++) trc[t] = trans[t*NTAG+tp];
        const float ent_tp = ent[tp];

        // per-batch valid length = sum(pm) (pm is a prefix mask)
        int part = 0;
        if (act) for (int l=tp; l<LSEQ; l+=NTAG) part += pm[b*LSEQ + l];
        int len = 0;
        #pragma unroll
        for (int t=0;t<NTAG;t++) len += __shfl(part, gbase + t, 64);

        // init at l=0
        float ev0 = act ? e[(size_t)b*NTAG + tp] : 0.f;
        float sn = stt[tp] + ev0;         // logZ state
        float sv = sn;                    // viterbi state

        // emissions prefetch ring (statically indexed)
        float evb[8];
        #pragma unroll
        for (int q=0;q<8;q++)
            evb[q] = act ? e[((size_t)(1+q)*BATCH + b)*NTAG + tp] : 0.f;

        unsigned char* hb = hist + (size_t)b*16 + tp;

        for (int l0=1; l0<LSEQ; l0+=8){
            #pragma unroll
            for (int q=0;q<8;q++){
                const int l = l0 + q;
                if (l < LSEQ) {
                    float ev = evb[q];
                    const int lp = l + 8;
                    evb[q] = (act && lp < LSEQ) ? e[((size_t)lp*BATCH + b)*NTAG + tp] : 0.f;

                    float an[NTAG], av[NTAG];
                    #pragma unroll
                    for (int t=0;t<NTAG;t++){
                        an[t] = __shfl(sn, gbase + t, 64) + trc[t];
                        av[t] = __shfl(sv, gbase + t, 64) + trc[t];
                    }
                    // logsumexp
                    float mx = an[0];
                    #pragma unroll
                    for (int t=1;t<NTAG;t++) mx = fmaxf(mx, an[t]);
                    float ss = 0.f;
                    #pragma unroll
                    for (int t=0;t<NTAG;t++) ss += __expf(an[t]-mx);
                    float nxt = mx + __logf(ss) + ev;
                    sn = (l < len) ? nxt : sn;
                    // viterbi, first-max strict > (matches jnp.argmax)
                    float bv = av[0]; int bi = 0;
                    #pragma unroll
                    for (int t=1;t<NTAG;t++){ if (av[t] > bv){ bv = av[t]; bi = t; } }
                    if (act) hb[(size_t)(l-1)*1024] = (unsigned char)bi;
                    sv = bv + ev;
                }
            }
        }

        // final reductions per batch (lane tp==0 of each group)
        float fz = sn + ent_tp;
        float fv = sv + ent_tp;
        float gz[NTAG], gv[NTAG];
        #pragma unroll
        for (int t=0;t<NTAG;t++){
            gz[t] = __shfl(fz, gbase + t, 64);
            gv[t] = __shfl(fv, gbase + t, 64);
        }
        if (act && tp == 0) {
            float mx = gz[0];
            #pragma unroll
            for (int t=1;t<NTAG;t++) mx = fmaxf(mx, gz[t]);
            float ss = 0.f;
            #pragma unroll
            for (int t=0;t<NTAG;t++) ss += __expf(gz[t]-mx);
            logZ[b] = mx + __logf(ss);
            float bv = gv[0]; int bi = 0;
            #pragma unroll
            for (int t=1;t<NTAG;t++){ if (gv[t] > bv){ bv = gv[t]; bi = t; } }
            bestl[b] = bi;
        }
    } else {
        // gold-path score, one lane per batch
        __shared__ float trl[NTAG*NTAG];
        __shared__ float stl[NTAG], enl[NTAG];
        for (int i=lane; i<NTAG*NTAG; i+=64) trl[i] = trans[i];
        if (lane < NTAG) { stl[lane] = stt[lane]; enl[lane] = ent[lane]; }
        __syncthreads();
        const int b = lane;
        int len = 0;
        for (int l=0; l<LSEQ; l+=4){
            int4 p = *(const int4*)&pm[b*LSEQ + l];
            len += p.x + p.y + p.z + p.w;
        }
        int tprev = tags[b*LSEQ];
        float acc = stl[tprev] + e[(size_t)b*NTAG + tprev];
        #pragma unroll 4
        for (int l=1; l<len; l++){
            int tl = tags[b*LSEQ + l];
            acc += trl[tprev*NTAG + tl] + e[((size_t)l*BATCH + b)*NTAG + tl];
            tprev = tl;
        }
        acc += enl[tprev];    // tags[len-1]
        num[b] = acc;
    }
}

// ---------------- Backtrace + loss ----------------
__global__ __launch_bounds__(64) void backtrace_kernel(
    const unsigned char* __restrict__ hist, const int* __restrict__ bestl,
    const int* __restrict__ pm, const float* __restrict__ num,
    const float* __restrict__ logZ, float* __restrict__ out)
{
    const int b = threadIdx.x;       // 0..63, one wave
    float d = num[b] - logZ[b];
    #pragma unroll
    for (int off=32; off; off>>=1) d += __shfl_down(d, off);
    if (b == 0) out[0] = -d * (1.0f/64.0f);
    int tag = bestl[b];
    out[1 + b*LSEQ + (LSEQ-1)] = (float)(tag * pm[b*LSEQ + (LSEQ-1)]);
    #pragma unroll 8
    for (int l = LSEQ-2; l >= 0; l--) {
        uint4 row = *(const uint4*)(hist + (size_t)l*1024 + b*16);  // addr independent of tag -> pipelined
        unsigned int wlo  = (tag & 4) ? row.y : row.x;
        unsigned int wsel = (tag & 8) ? row.z : wlo;
        tag = (int)((wsel >> ((tag & 3) * 8)) & 255u);
        out[1 + b*LSEQ + l] = (float)(tag * pm[b*LSEQ + l]);
    }
}

extern "C" void kernel_launch(void* const* d_in, const int* in_sizes, int n_in,
                              void* d_out, int out_size, void* d_ws, size_t ws_size,
                              hipStream_t stream)
{
    (void)in_sizes; (void)n_in; (void)out_size; (void)ws_size;
    const int*   sent  = (const int*)  d_in[0];
    const int*   tags  = (const int*)  d_in[1];
    const int*   pm    = (const int*)  d_in[2];
    // d_in[3] = batch_sequence_max_len (== 512)
    const float* emb   = (const float*)d_in[4];
    const float* wihf  = (const float*)d_in[5];
    const float* whhf  = (const float*)d_in[6];
    const float* bf    = (const float*)d_in[7];
    const float* wihb  = (const float*)d_in[8];
    const float* whhb  = (const float*)d_in[9];
    const float* bb    = (const float*)d_in[10];
    const float* Wo    = (const float*)d_in[11];
    const float* bo    = (const float*)d_in[12];
    const float* stt   = (const float*)d_in[13];
    const float* ent   = (const float*)d_in[14];
    const float* trans = (const float*)d_in[15];

    char* ws = (char*)d_ws;
    float* gx            = (float*)(ws);                       // 2*32768*512*4   = 134217728 B
    float* lout          = (float*)(ws + 134217728);           // 32768*256*4     =  33554432 B
    float* emis          = (float*)(ws + 167772160);           // 32768*9*4       =   1179648 B
    unsigned char* hist  = (unsigned char*)(ws + 168951808);   // 511*64*16       =    523264 B
    float* numb          = (float*)(ws + 169475072);           // 64*4
    float* logZ          = (float*)(ws + 169475328);           // 64*4
    int*   bestl         = (int*)  (ws + 169475584);           // 64*4

    dim3 g1(MTOT/BM, (2*G4)/BN);   // 512 x 16
    gx_gemm<<<g1, 256, 0, stream>>>(sent, emb, wihf, wihb, bf, bb, gx);
    lstm_rec<<<128, 512, 0, stream>>>(gx, whhf, whhb, pm, lout);
    emis_kernel<<<MTOT/32, 256, 0, stream>>>(lout, Wo, bo, emis);
    crf_scan<<<11, 64, 0, stream>>>(emis, pm, tags, stt, ent, trans, logZ, numb, hist, bestl);
    backtrace_kernel<<<1, 64, 0, stream>>>(hist, bestl, pm, numb, logZ, (float*)d_out);
}

// Round 3
// 796.849 us; speedup vs baseline: 1.7226x; 1.2523x over previous
//
#include <hip/hip_runtime.h>
#include <math.h>

#define LSEQ 512
#define BATCH 64
#define EDIM 256
#define HD 128            // H2
#define G4 512            // 4*H2
#define NTAG 9
#define MTOT (LSEQ*BATCH) // 32768

typedef _Float16 f16x8 __attribute__((ext_vector_type(8)));
typedef float    f32x4 __attribute__((ext_vector_type(4)));

__device__ __forceinline__ float fsig(float x){
    return __builtin_amdgcn_rcpf(1.0f + __expf(-x));
}
__device__ __forceinline__ float ftanh(float x){
    return 1.0f - 2.0f*__builtin_amdgcn_rcpf(1.0f + __expf(2.0f*x));
}
// LDS-only barrier: does NOT drain vmcnt, so global prefetches stay in flight.
__device__ __forceinline__ void wg_barrier_lds(){
    asm volatile("s_waitcnt lgkmcnt(0)" ::: "memory");
    __builtin_amdgcn_s_barrier();
    asm volatile("" ::: "memory");
}

// ---------------- GEMM (MFMA, f16 3-term split): gx[dir][l*64+b][j] = emb[sent[b][l]] . w_ih[j] + bias
// x = h + m exactly to ~2^-24: h = f16(x), m = f16(x - h). Keep hh + hm + mh (drop mm ~2^-24).
#define GBM 128
#define GBN 128
#define GBK 32
__global__ __launch_bounds__(256) void gx_gemm(
    const int* __restrict__ sent, const float* __restrict__ emb,
    const float* __restrict__ wf, const float* __restrict__ wb,
    const float* __restrict__ bf, const float* __restrict__ bb,
    float* __restrict__ gx)
{
    // fragment-layout LDS: region = 8 tiles (16 rows x 32 k) x 64 lanes x 16B
    __shared__ f16x8 Ah[512], Am[512], Bh[512], Bm[512];
    __shared__ int sidx[GBM];
    const int tid = threadIdx.x;
    const int bm0 = blockIdx.x * GBM;
    const int bn0 = blockIdx.y * GBN;
    if (tid < GBM){
        int m = bm0 + tid;
        sidx[tid] = sent[(m & 63)*LSEQ + (m >> 6)];
    }
    __syncthreads();

    // per-thread constant source pointers for the 2 staging passes
    const float* srcA[2];
    const float* srcB[2];
    #pragma unroll
    for (int p=0;p<2;p++){
        const int d   = tid + 256*p;          // LDS 16B-chunk index 0..511
        const int row = (d>>6)*16 + (d&15);   // fragment: row-in-tile = lane&15
        const int kq  = (d>>4)&3;             // fragment: k-group = lane>>4
        srcA[p] = emb + (size_t)sidx[row]*EDIM + kq*8;
        const int col = bn0 + row;
        srcB[p] = ((col < G4) ? (wf + (size_t)col*EDIM)
                              : (wb + (size_t)(col-G4)*EDIM)) + kq*8;
    }

    const int lane = tid & 63;
    const int wid  = tid >> 6;
    const int wm   = wid >> 1;   // 0..1 : 64-row half
    const int wn   = wid & 1;    // 0..1 : 64-col half

    f32x4 acc[4][4];
    #pragma unroll
    for (int i=0;i<4;i++)
        #pragma unroll
        for (int jj=0;jj<4;jj++)
            #pragma unroll
            for (int e=0;e<4;e++) acc[i][jj][e]=0.f;

    float4 ra[2][2], rb[2][2];
    #define LOADC(K0)  { _Pragma("unroll") for (int p=0;p<2;p++){ \
        ra[p][0] = *(const float4*)(srcA[p] + (K0));  ra[p][1] = *(const float4*)(srcA[p] + (K0) + 4); \
        rb[p][0] = *(const float4*)(srcB[p] + (K0));  rb[p][1] = *(const float4*)(srcB[p] + (K0) + 4); } }

    LOADC(0);
    for (int c=0;c<8;c++){
        wg_barrier_lds();                       // prior compute's LDS reads drained
        #pragma unroll
        for (int p=0;p<2;p++){
            float va[8] = {ra[p][0].x, ra[p][0].y, ra[p][0].z, ra[p][0].w,
                           ra[p][1].x, ra[p][1].y, ra[p][1].z, ra[p][1].w};
            float vb[8] = {rb[p][0].x, rb[p][0].y, rb[p][0].z, rb[p][0].w,
                           rb[p][1].x, rb[p][1].y, rb[p][1].z, rb[p][1].w};
            f16x8 ahh, amm, bhh, bmm;
            #pragma unroll
            for (int i=0;i<8;i++){
                _Float16 hv = (_Float16)va[i];
                ahh[i] = hv; amm[i] = (_Float16)(va[i] - (float)hv);
                _Float16 hw = (_Float16)vb[i];
                bhh[i] = hw; bmm[i] = (_Float16)(vb[i] - (float)hw);
            }
            Ah[tid + 256*p] = ahh;  Am[tid + 256*p] = amm;
            Bh[tid + 256*p] = bhh;  Bm[tid + 256*p] = bmm;
        }
        if (c < 7) LOADC(32*(c+1));             // prefetch next chunk (flies over compute)
        wg_barrier_lds();                       // staging visible

        f16x8 ah[4], am[4];
        #pragma unroll
        for (int mt=0;mt<4;mt++){
            ah[mt] = Ah[(wm*4+mt)*64 + lane];
            am[mt] = Am[(wm*4+mt)*64 + lane];
        }
        #pragma unroll
        for (int nt=0;nt<4;nt++){
            f16x8 bh = Bh[(wn*4+nt)*64 + lane];
            f16x8 bm = Bm[(wn*4+nt)*64 + lane];
            #pragma unroll
            for (int mt=0;mt<4;mt++){
                acc[mt][nt] = __builtin_amdgcn_mfma_f32_16x16x32_f16(ah[mt], bh, acc[mt][nt], 0,0,0);
                acc[mt][nt] = __builtin_amdgcn_mfma_f32_16x16x32_f16(am[mt], bh, acc[mt][nt], 0,0,0);
                acc[mt][nt] = __builtin_amdgcn_mfma_f32_16x16x32_f16(ah[mt], bm, acc[mt][nt], 0,0,0);
            }
        }
    }
    #undef LOADC

    // epilogue: C/D frag: col = lane&15, row = (lane>>4)*4 + e  [m89-verified]
    #pragma unroll
    for (int mt=0;mt<4;mt++){
        #pragma unroll
        for (int nt=0;nt<4;nt++){
            const int n   = bn0 + wn*64 + nt*16 + (lane & 15);
            const int dir = n >> 9;
            const int j   = n & 511;
            const float bias = (n < G4) ? bf[n] : bb[n - G4];
            const int mrow = bm0 + wm*64 + mt*16 + ((lane >> 4) << 2);
            float* o = gx + (size_t)dir*((size_t)MTOT*G4) + (size_t)mrow*G4 + j;
            o[0*G4] = acc[mt][nt][0] + bias;
            o[1*G4] = acc[mt][nt][1] + bias;
            o[2*G4] = acc[mt][nt][2] + bias;
            o[3*G4] = acc[mt][nt][3] + bias;
        }
    }
}

// ---------------- LSTM recurrence: 128 WGs = (dir, b); 2-way K-split, gx register prefetch ----------------
__global__ __launch_bounds__(512) void lstm_rec(
    const float* __restrict__ gx,
    const float* __restrict__ whf, const float* __restrict__ whb,
    const int* __restrict__ pm,
    float* __restrict__ lout)
{
    const int wg  = blockIdx.x;      // 0..127
    const int dir = wg >> 6;
    const int b   = wg & 63;
    const int t   = threadIdx.x;     // 0..511
    const int kh  = t >> 8;          // K-half 0/1
    const int gr  = t & 255;         // this thread: gate-rows gr and gr+256, k in [kh*64, kh*64+64)
    const int j   = t & 127;         // unit index for update phase (t<128)

    const float* wbase = dir ? whb : whf;
    float w0[64], w1[64];
    {
        const float* r0 = wbase + (size_t)gr*HD       + kh*64;
        const float* r1 = wbase + (size_t)(gr+256)*HD + kh*64;
        #pragma unroll
        for (int k=0;k<64;k+=4){
            float4 v = *(const float4*)(r0+k);
            w0[k]=v.x; w0[k+1]=v.y; w0[k+2]=v.z; w0[k+3]=v.w;
            float4 u = *(const float4*)(r1+k);
            w1[k]=u.x; w1[k+1]=u.y; w1[k+2]=u.z; w1[k+3]=u.w;
        }
    }
    __shared__ float hsh[HD];
    __shared__ float pact[2][512];
    __shared__ int   pms[LSEQ];
    for (int q=t; q<LSEQ; q+=512) pms[q] = pm[b*LSEQ + q];
    if (t < HD) hsh[t] = 0.f;
    float c = 0.f, h = 0.f;

    const size_t stepel = (size_t)BATCH*G4;
    const float* gxb = gx + (size_t)dir*((size_t)MTOT*G4) + (size_t)b*G4
                          + (dir ? (size_t)(LSEQ-1)*stepel : 0);
    const ptrdiff_t dstep = dir ? -(ptrdiff_t)stepel : (ptrdiff_t)stepel;
    float* op = lout + (size_t)b*256 + dir*HD + j;   // used only when t<128

    float4 gc = {0,0,0,0};
    if (t < 128){
        gc.x = gxb[j]; gc.y = gxb[j+128]; gc.z = gxb[j+256]; gc.w = gxb[j+384];
    }
    wg_barrier_lds();   // hsh + pms visible

    for (int s=0; s<LSEQ; s++){
        // prefetch next step's gx (independent of recurrence; vmcnt never drained at our barriers)
        float4 gn = {0,0,0,0};
        if (t < 128 && s+1 < LSEQ){
            const float* p = gxb + (ptrdiff_t)(s+1)*dstep;
            gn.x = p[j]; gn.y = p[j+128]; gn.z = p[j+256]; gn.w = p[j+384];
        }
        const int l = dir ? (LSEQ-1-s) : s;
        const int pmv = pms[l];          // LDS read hidden under the dot phase

        float a0=0.f,a1=0.f,b0=0.f,b1=0.f;
        const float* hp = &hsh[kh*64];
        #pragma unroll
        for (int k=0;k<64;k+=8){
            float4 x0 = *(const float4*)(hp+k);
            float4 x1 = *(const float4*)(hp+k+4);
            a0 += x0.x*w0[k+0] + x0.y*w0[k+1] + x0.z*w0[k+2] + x0.w*w0[k+3];
            a1 += x1.x*w0[k+4] + x1.y*w0[k+5] + x1.z*w0[k+6] + x1.w*w0[k+7];
            b0 += x0.x*w1[k+0] + x0.y*w1[k+1] + x0.z*w1[k+2] + x0.w*w1[k+3];
            b1 += x1.x*w1[k+4] + x1.y*w1[k+5] + x1.z*w1[k+6] + x1.w*w1[k+7];
        }
        pact[kh][gr]     = a0 + a1;
        pact[kh][gr+256] = b0 + b1;
        wg_barrier_lds();

        if (t < 128){
            float p0 = gc.x + pact[0][j]     + pact[1][j];
            float p1 = gc.y + pact[0][j+128] + pact[1][j+128];
            float p2 = gc.z + pact[0][j+256] + pact[1][j+256];
            float p3 = gc.w + pact[0][j+384] + pact[1][j+384];
            float i_ = fsig(p0), f_ = fsig(p1), g_ = ftanh(p2), o_ = fsig(p3);
            float cn = f_*c + i_*g_;
            float hn = o_*ftanh(cn);
            float y;
            if (pmv) { c = cn; h = hn; y = hn; } else { y = 0.f; }
            hsh[j] = h;
            op[(size_t)l*(BATCH*256)] = y;
        }
        wg_barrier_lds();
        gc = gn;
    }
}

// ---------------- Emissions: e[m][t] = lout[m] . W_out[t] + b_out[t] ----------------
__global__ __launch_bounds__(256) void emis_kernel(
    const float* __restrict__ xin, const float* __restrict__ Wo,
    const float* __restrict__ bo, float* __restrict__ e)
{
    __shared__ float Wl[NTAG*260];
    const int tid = threadIdx.x;
    for (int i=tid; i<NTAG*256; i+=256) Wl[(i>>8)*260 + (i&255)] = Wo[i];
    __syncthreads();
    const int m0 = blockIdx.x * 32;
    const int tg = tid & 7;
    const int r  = tid >> 3;
    const float* xr = xin + (size_t)(m0 + r) * 256;
    float a0=0.f, a1=0.f;
    #pragma unroll 8
    for (int k=0;k<256;k+=4){
        float4 xv = *(const float4*)(xr + k);
        float4 w0 = *(const float4*)&Wl[tg*260 + k];
        a0 += xv.x*w0.x + xv.y*w0.y + xv.z*w0.z + xv.w*w0.w;
        if (tg == 0) {
            float4 w8 = *(const float4*)&Wl[8*260 + k];
            a1 += xv.x*w8.x + xv.y*w8.y + xv.z*w8.z + xv.w*w8.w;
        }
    }
    e[(size_t)(m0+r)*NTAG + tg] = a0 + bo[tg];
    if (tg == 0) e[(size_t)(m0+r)*NTAG + 8] = a1 + bo[8];
}

// ---------------- CRF scan: barrier-free wave-local (same as round 2, passing) ----------------
__global__ __launch_bounds__(64) void crf_scan(
    const float* __restrict__ e, const int* __restrict__ pm,
    const int* __restrict__ tags,
    const float* __restrict__ stt, const float* __restrict__ ent,
    const float* __restrict__ trans,
    float* __restrict__ logZ, float* __restrict__ num,
    unsigned char* __restrict__ hist, int* __restrict__ bestl)
{
    const int blk  = blockIdx.x;
    const int lane = threadIdx.x;

    if (blk < 10) {
        const int bw = lane / 9;
        const int tp = lane % 9;
        const int b  = blk * 7 + bw;
        const bool act = (bw < 7) && (b < BATCH);
        const int gbase = bw * 9;

        float trc[NTAG];
        #pragma unroll
        for (int t=0;t<NTAG;t++) trc[t] = trans[t*NTAG+tp];
        const float ent_tp = ent[tp];

        int part = 0;
        if (act) for (int l=tp; l<LSEQ; l+=NTAG) part += pm[b*LSEQ + l];
        int len = 0;
        #pragma unroll
        for (int t=0;t<NTAG;t++) len += __shfl(part, gbase + t, 64);

        float ev0 = act ? e[(size_t)b*NTAG + tp] : 0.f;
        float sn = stt[tp] + ev0;
        float sv = sn;

        float evb[8];
        #pragma unroll
        for (int q=0;q<8;q++)
            evb[q] = act ? e[((size_t)(1+q)*BATCH + b)*NTAG + tp] : 0.f;

        unsigned char* hb = hist + (size_t)b*16 + tp;

        for (int l0=1; l0<LSEQ; l0+=8){
            #pragma unroll
            for (int q=0;q<8;q++){
                const int l = l0 + q;
                if (l < LSEQ) {
                    float ev = evb[q];
                    const int lp = l + 8;
                    evb[q] = (act && lp < LSEQ) ? e[((size_t)lp*BATCH + b)*NTAG + tp] : 0.f;

                    float an[NTAG], av[NTAG];
                    #pragma unroll
                    for (int t=0;t<NTAG;t++){
                        an[t] = __shfl(sn, gbase + t, 64) + trc[t];
                        av[t] = __shfl(sv, gbase + t, 64) + trc[t];
                    }
                    float mx = an[0];
                    #pragma unroll
                    for (int t=1;t<NTAG;t++) mx = fmaxf(mx, an[t]);
                    float ss = 0.f;
                    #pragma unroll
                    for (int t=0;t<NTAG;t++) ss += __expf(an[t]-mx);
                    float nxt = mx + __logf(ss) + ev;
                    sn = (l < len) ? nxt : sn;
                    float bv = av[0]; int bi = 0;
                    #pragma unroll
                    for (int t=1;t<NTAG;t++){ if (av[t] > bv){ bv = av[t]; bi = t; } }
                    if (act) hb[(size_t)(l-1)*1024] = (unsigned char)bi;
                    sv = bv + ev;
                }
            }
        }

        float fz = sn + ent_tp;
        float fv = sv + ent_tp;
        float gz[NTAG], gv[NTAG];
        #pragma unroll
        for (int t=0;t<NTAG;t++){
            gz[t] = __shfl(fz, gbase + t, 64);
            gv[t] = __shfl(fv, gbase + t, 64);
        }
        if (act && tp == 0) {
            float mx = gz[0];
            #pragma unroll
            for (int t=1;t<NTAG;t++) mx = fmaxf(mx, gz[t]);
            float ss = 0.f;
            #pragma unroll
            for (int t=0;t<NTAG;t++) ss += __expf(gz[t]-mx);
            logZ[b] = mx + __logf(ss);
            float bv = gv[0]; int bi = 0;
            #pragma unroll
            for (int t=1;t<NTAG;t++){ if (gv[t] > bv){ bv = gv[t]; bi = t; } }
            bestl[b] = bi;
        }
    } else {
        __shared__ float trl[NTAG*NTAG];
        __shared__ float stl[NTAG], enl[NTAG];
        for (int i=lane; i<NTAG*NTAG; i+=64) trl[i] = trans[i];
        if (lane < NTAG) { stl[lane] = stt[lane]; enl[lane] = ent[lane]; }
        __syncthreads();
        const int b = lane;
        int len = 0;
        for (int l=0; l<LSEQ; l+=4){
            int4 p = *(const int4*)&pm[b*LSEQ + l];
            len += p.x + p.y + p.z + p.w;
        }
        int tprev = tags[b*LSEQ];
        float acc = stl[tprev] + e[(size_t)b*NTAG + tprev];
        #pragma unroll 4
        for (int l=1; l<len; l++){
            int tl = tags[b*LSEQ + l];
            acc += trl[tprev*NTAG + tl] + e[((size_t)l*BATCH + b)*NTAG + tl];
            tprev = tl;
        }
        acc += enl[tprev];
        num[b] = acc;
    }
}

// ---------------- Backtrace + loss ----------------
__global__ __launch_bounds__(64) void backtrace_kernel(
    const unsigned char* __restrict__ hist, const int* __restrict__ bestl,
    const int* __restrict__ pm, const float* __restrict__ num,
    const float* __restrict__ logZ, float* __restrict__ out)
{
    const int b = threadIdx.x;
    float d = num[b] - logZ[b];
    #pragma unroll
    for (int off=32; off; off>>=1) d += __shfl_down(d, off);
    if (b == 0) out[0] = -d * (1.0f/64.0f);
    int tag = bestl[b];
    out[1 + b*LSEQ + (LSEQ-1)] = (float)(tag * pm[b*LSEQ + (LSEQ-1)]);
    #pragma unroll 8
    for (int l = LSEQ-2; l >= 0; l--) {
        uint4 row = *(const uint4*)(hist + (size_t)l*1024 + b*16);
        unsigned int wlo  = (tag & 4) ? row.y : row.x;
        unsigned int wsel = (tag & 8) ? row.z : wlo;
        tag = (int)((wsel >> ((tag & 3) * 8)) & 255u);
        out[1 + b*LSEQ + l] = (float)(tag * pm[b*LSEQ + l]);
    }
}

extern "C" void kernel_launch(void* const* d_in, const int* in_sizes, int n_in,
                              void* d_out, int out_size, void* d_ws, size_t ws_size,
                              hipStream_t stream)
{
    (void)in_sizes; (void)n_in; (void)out_size; (void)ws_size;
    const int*   sent  = (const int*)  d_in[0];
    const int*   tags  = (const int*)  d_in[1];
    const int*   pm    = (const int*)  d_in[2];
    const float* emb   = (const float*)d_in[4];
    const float* wihf  = (const float*)d_in[5];
    const float* whhf  = (const float*)d_in[6];
    const float* bf    = (const float*)d_in[7];
    const float* wihb  = (const float*)d_in[8];
    const float* whhb  = (const float*)d_in[9];
    const float* bb    = (const float*)d_in[10];
    const float* Wo    = (const float*)d_in[11];
    const float* bo    = (const float*)d_in[12];
    const float* stt   = (const float*)d_in[13];
    const float* ent   = (const float*)d_in[14];
    const float* trans = (const float*)d_in[15];

    char* ws = (char*)d_ws;
    float* gx            = (float*)(ws);                       // 134217728 B
    float* lout          = (float*)(ws + 134217728);           //  33554432 B
    float* emis          = (float*)(ws + 167772160);           //   1179648 B
    unsigned char* hist  = (unsigned char*)(ws + 168951808);   //    523264 B
    float* numb          = (float*)(ws + 169475072);
    float* logZ          = (float*)(ws + 169475328);
    int*   bestl         = (int*)  (ws + 169475584);

    dim3 g1(MTOT/GBM, (2*G4)/GBN);   // 256 x 8
    gx_gemm<<<g1, 256, 0, stream>>>(sent, emb, wihf, wihb, bf, bb, gx);
    lstm_rec<<<128, 512, 0, stream>>>(gx, whhf, whhb, pm, lout);
    emis_kernel<<<MTOT/32, 256, 0, stream>>>(lout, Wo, bo, emis);
    crf_scan<<<11, 64, 0, stream>>>(emis, pm, tags, stt, ent, trans, logZ, numb, hist, bestl);
    backtrace_kernel<<<1, 64, 0, stream>>>(hist, bestl, pm, numb, logZ, (float*)d_out);
}